// Round 3
// baseline (224.976 us; speedup 1.0000x reference)
//
#include <hip/hip_runtime.h>
#include <stdint.h>

// Problem constants (from reference)
#define B_SZ   512
#define T_SZ   100
#define NPRE   256
#define NPOST  256
#define KTOT   (B_SZ * T_SZ)   // 51200

typedef __bf16 bf16x8 __attribute__((ext_vector_type(8)));
typedef float  floatx4 __attribute__((ext_vector_type(4)));

// ---------------------------------------------------------------------------
// Fused kernel: per block = 4 whole batches (K-split, scan is batch-local)
// x 1 p-tile (128 of 256 p) x full q (256).
// Per batch: {scan pre->A_lds (threads 0-127) || stage post->B_lds (rest)}
// barrier, then 4 MFMA chunks (K=100 zero-padded to 128).
// A_lds/B_lds hold MFMA-native fragment lines: line = 64 lanes x 8 bf16
// (16 B/lane) -> every frag access is one aligned b128, full-sweep banks.
//   A line (kc,pg): lane l holds A[p=pg*16+(l&15)][k=kc*32+(l>>4)*8+j]
//   B line (kc,qg): lane l holds B[k=kc*32+(l>>4)*8+j][q=qg*16+(l&15)]
// ---------------------------------------------------------------------------
__global__ __launch_bounds__(512, 2) void stdp_fused_gemm(
    const float* __restrict__ pre, const float* __restrict__ post,
    float* __restrict__ partial)
{
    __shared__ __align__(16) unsigned short A_lds[16384];  // 32 lines * 512 = 32 KB
    __shared__ __align__(16) unsigned short B_lds[32768];  // 64 lines * 512 = 64 KB

    const int bx  = blockIdx.x;   // 0..255
    const int s   = bx >> 1;      // K-split: batches 4s..4s+3
    const int pt  = bx & 1;       // p-tile
    const int tid = threadIdx.x;
    const int lane = tid & 63;
    const int wave = tid >> 6;    // 0..7
    const int wp = wave & 3;      // 32-row region
    const int wq = wave >> 2;     // 128-col region
    const int l15 = lane & 15;
    const int l4  = lane >> 4;

    floatx4 acc[2][8] = {};

    for (int lb = 0; lb < 4; ++lb) {
        const int b = s * 4 + lb;

        if (tid < 128) {
            // ---- scan: trace for p-tile, batch b ----
            const int p = tid;
            const int pg = p >> 4;
            const float decay = 0.95122942450071400910f;  // expf(-1/20)
            const float* src = pre + (size_t)b * (T_SZ * NPRE) + pt * 128 + p;
            float carry = 0.0f;
            for (int t0 = 0; t0 < T_SZ; t0 += 20) {
                float x[20];
#pragma unroll
                for (int j = 0; j < 20; ++j)
                    x[j] = src[(size_t)(t0 + j) * NPRE];
#pragma unroll
                for (int g = 0; g < 10; ++g) {
                    // emit trace[t] = carry (RNE->bf16), then update; pack 2 t's
                    uint32_t bits = __float_as_uint(carry);
                    uint32_t lo = (bits + 0x7FFFu + ((bits >> 16) & 1u)) >> 16;
                    carry = decay * (carry + x[g * 2]);
                    bits = __float_as_uint(carry);
                    uint32_t hi = (bits + 0x7FFFu + ((bits >> 16) & 1u)) >> 16;
                    carry = decay * (carry + x[g * 2 + 1]);
                    int t = t0 + g * 2;
                    int kc = t >> 5, sl = ((t >> 3) & 3) * 16 + (p & 15), j7 = t & 7;
                    *(uint32_t*)(A_lds + (((kc * 8 + pg) * 64 + sl) << 3) + j7) =
                        lo | (hi << 16);
                }
            }
            // zero-pad t = 100..127
#pragma unroll
            for (int t = 100; t < 128; t += 2) {
                int kc = t >> 5, sl = ((t >> 3) & 3) * 16 + (p & 15), j7 = t & 7;
                *(uint32_t*)(A_lds + (((kc * 8 + pg) * 64 + sl) << 3) + j7) = 0u;
            }
        } else {
            // ---- B-stage: post[b] -> bf16 fragment lines (truncate, exact) ----
            for (int r = 0; r < 3; ++r) {
                int u = (tid - 128) + 384 * r;
                if (u < 1024) {
                    int q  = u & 255;
                    int og = u >> 8;        // kc tile; t in [og*32, og*32+32)
                    int qg = q >> 4;
                    const float* srcb = post + (size_t)b * (T_SZ * NPOST) + q;
#pragma unroll
                    for (int o = 0; o < 4; ++o) {   // t-oct within tile
                        uint32_t pk[4];
#pragma unroll
                        for (int jj = 0; jj < 4; ++jj) {
                            int t = og * 32 + o * 8 + jj * 2;
                            float x0 = (t < T_SZ)     ? srcb[(size_t)t * NPOST]       : 0.0f;
                            float x1 = (t + 1 < T_SZ) ? srcb[(size_t)(t + 1) * NPOST] : 0.0f;
                            pk[jj] = (__float_as_uint(x0) >> 16) |
                                     (__float_as_uint(x1) & 0xFFFF0000u);
                        }
                        *(uint4*)(B_lds + (((og * 16 + qg) * 64 + o * 16 + (q & 15)) << 3)) =
                            make_uint4(pk[0], pk[1], pk[2], pk[3]);
                    }
                }
            }
        }
        __syncthreads();

        // ---- GEMM: 4 chunks of K=32 ----
#pragma unroll
        for (int kc = 0; kc < 4; ++kc) {
            bf16x8 a[2], bb[8];
#pragma unroll
            for (int f = 0; f < 2; ++f)
                a[f] = *(const bf16x8*)(A_lds + (((kc * 8 + wp * 2 + f) * 64 + lane) << 3));
#pragma unroll
            for (int g = 0; g < 8; ++g)
                bb[g] = *(const bf16x8*)(B_lds + (((kc * 16 + wq * 8 + g) * 64 + lane) << 3));
#pragma unroll
            for (int f = 0; f < 2; ++f)
#pragma unroll
                for (int g = 0; g < 8; ++g)
                    acc[f][g] = __builtin_amdgcn_mfma_f32_16x16x32_bf16(
                        a[f], bb[g], acc[f][g], 0, 0, 0);
        }
        __syncthreads();
    }

    // ---- writeout: partial[bx][p_loc 128][q 256] ----
    // C/D layout (m89/m91): col = lane&15, row = (lane>>4)*4 + reg
    float* pout = partial + (size_t)bx * (128 * 256);
#pragma unroll
    for (int f = 0; f < 2; ++f) {
        int r0 = wp * 32 + f * 16 + l4 * 4;
#pragma unroll
        for (int g = 0; g < 8; ++g) {
            int c = wq * 128 + g * 16 + l15;
#pragma unroll
            for (int v = 0; v < 4; ++v)
                pout[(size_t)(r0 + v) * 256 + c] = acc[f][g][v];
        }
    }
}

// ---------------------------------------------------------------------------
// Reduce stage 1: 128 K-splits -> 8 groups of 16. e = [pt][p_loc][q].
// ---------------------------------------------------------------------------
__global__ __launch_bounds__(256) void stdp_reduce1_kernel(
    const float* __restrict__ partial, float* __restrict__ tmp)
{
    const int t = blockIdx.x * 256 + threadIdx.x;  // 0..524287
    const int g = t >> 16;                         // 0..7
    const int e = t & 65535;
    const int pt = e >> 15;
    const int i  = e & 32767;
    const float* src = partial + ((size_t)(g * 16) * 2 + pt) * 32768 + i;
    float s = 0.0f;
#pragma unroll
    for (int j = 0; j < 16; ++j)
        s += src[(size_t)j * 65536];
    tmp[t] = s;
}

// ---------------------------------------------------------------------------
// Reduce stage 2: 8 -> 1, un-tile, scale by (A+ - A-)/(B*T).
// ---------------------------------------------------------------------------
__global__ __launch_bounds__(256) void stdp_reduce2_kernel(
    const float* __restrict__ tmp, float* __restrict__ out)
{
    const int idx = blockIdx.x * 256 + threadIdx.x;  // 0..65535
    const int P = idx >> 8, Q = idx & 255;
    const int e = (P >> 7) * 32768 + (P & 127) * 256 + Q;
    float s = 0.0f;
#pragma unroll
    for (int g = 0; g < 8; ++g)
        s += tmp[(size_t)g * 65536 + e];
    const float scale = (0.005f - 0.00525f) * (1.0f / (float)KTOT);
    out[idx] = s * scale;
}

// ---------------------------------------------------------------------------
extern "C" void kernel_launch(void* const* d_in, const int* in_sizes, int n_in,
                              void* d_out, int out_size, void* d_ws, size_t ws_size,
                              hipStream_t stream)
{
    const float* pre  = (const float*)d_in[0];   // [512,100,256]
    const float* post = (const float*)d_in[1];   // [512,100,256]
    float* out = (float*)d_out;                  // [256,256]

    float* partial = (float*)d_ws;                               // 256*128*256*4 = 33,554,432 B
    float* tmp     = (float*)((char*)d_ws + (size_t)33554432);   // 8*65536*4    =  2,097,152 B

    stdp_fused_gemm<<<256, 512, 0, stream>>>(pre, post, partial);
    stdp_reduce1_kernel<<<2048, 256, 0, stream>>>(partial, tmp);
    stdp_reduce2_kernel<<<256, 256, 0, stream>>>(tmp, out);
}

// Round 4
// 151.881 us; speedup vs baseline: 1.4813x; 1.4813x over previous
//
#include <hip/hip_runtime.h>
#include <stdint.h>

// Problem constants (from reference)
#define B_SZ   512
#define T_SZ   100
#define NPRE   256
#define NPOST  256
#define KTOT   (B_SZ * T_SZ)   // 51200

typedef __bf16 bf16x8 __attribute__((ext_vector_type(8)));
typedef float  floatx4 __attribute__((ext_vector_type(4)));

__device__ __forceinline__ uint32_t pack_rne2(float a_done, uint32_t lo) {
    (void)a_done; return lo;  // unused helper placeholder
}
__device__ __forceinline__ uint32_t bf16_rne(float v) {
    uint32_t bits = __float_as_uint(v);
    return (bits + 0x7FFFu + ((bits >> 16) & 1u)) >> 16;
}
__device__ __forceinline__ uint32_t pack_trunc2(float a, float b) {
    return (__float_as_uint(a) >> 16) | (__float_as_uint(b) & 0xFFFF0000u);
}

// ---------------------------------------------------------------------------
// Kernel 1: trace prep. block = batch (512 blocks x 256 thr; thread = p).
// Serial fp32 scan in t-chunks {32,32,32,4->pad}, flat unconditional loads,
// LDS transpose, then contiguous 1 KB fragment-line stores:
//   line (kc' = b*4+kc, pg): lane l holds trace[t=kc*32+(l>>4)*8+j][p=pg*16+(l&15)]
//   t in [100,128) stored as zero.
// ---------------------------------------------------------------------------
__global__ __launch_bounds__(256) void stdp_trace_prep(
    const float* __restrict__ pre, unsigned short* __restrict__ trace_t)
{
    __shared__ __align__(16) unsigned short T_lds[4][256][8];  // [o][p][j] = 16 KB

    const int b = blockIdx.x;
    const int p = threadIdx.x;
    const int lane = p & 63, wave = p >> 6;
    const float decay = 0.95122942450071400910f;  // expf(-1/20)
    const float* src = pre + (size_t)b * (T_SZ * NPRE) + p;

    float carry = 0.0f;
    for (int kc = 0; kc < 4; ++kc) {
        uint32_t pk[16];
        if (kc < 3) {
            float x[32];
#pragma unroll
            for (int j = 0; j < 32; ++j)
                x[j] = src[(size_t)(kc * 32 + j) * NPRE];
#pragma unroll
            for (int j = 0; j < 16; ++j) {
                uint32_t lo = bf16_rne(carry);          // trace[t] = carry, then update
                carry = decay * (carry + x[2 * j]);
                uint32_t hi = bf16_rne(carry);
                carry = decay * (carry + x[2 * j + 1]);
                pk[j] = lo | (hi << 16);
            }
        } else {
            float x[4];
#pragma unroll
            for (int j = 0; j < 4; ++j)
                x[j] = src[(size_t)(96 + j) * NPRE];
#pragma unroll
            for (int j = 0; j < 2; ++j) {
                uint32_t lo = bf16_rne(carry);
                carry = decay * (carry + x[2 * j]);
                uint32_t hi = bf16_rne(carry);
                carry = decay * (carry + x[2 * j + 1]);
                pk[j] = lo | (hi << 16);
            }
#pragma unroll
            for (int j = 2; j < 16; ++j) pk[j] = 0u;    // t >= 100 -> zero
        }
        // LDS: [o][p][8] — lane-contiguous 16 B writes (conflict-free)
#pragma unroll
        for (int o = 0; o < 4; ++o)
            *(uint4*)&T_lds[o][p][0] =
                make_uint4(pk[o * 4], pk[o * 4 + 1], pk[o * 4 + 2], pk[o * 4 + 3]);
        __syncthreads();
        // 16 lines / 4 waves: wave stores 4 consecutive 1 KB lines
#pragma unroll
        for (int i = 0; i < 4; ++i) {
            int pg = wave * 4 + i;
            uint4 v = *(const uint4*)&T_lds[lane >> 4][pg * 16 + (lane & 15)][0];
            *(uint4*)(trace_t + (((size_t)(b * 4 + kc) * 16 + pg) << 9) + lane * 8) = v;
        }
        __syncthreads();
    }
}

// ---------------------------------------------------------------------------
// Kernel 2: split-K MFMA GEMM. 256 blocks = 128 K-splits (4 batches) x 2
// p-tiles; tile 128p x 256q; 512 thr (8 waves: wp 0..3 x wq 0..1).
// A: per-batch prefetched 1 KB-line dwordx4 global loads from trace_t.
// B: staged fp32 post -> bf16 LDS lines (flat unconditional load batches,
// truncation exact for {0,1}; t>=100 zero).
// ---------------------------------------------------------------------------
__global__ __launch_bounds__(512) void stdp_gemm(
    const unsigned short* __restrict__ trace_t,
    const float* __restrict__ post,
    float* __restrict__ partial)
{
    __shared__ __align__(16) unsigned short B_lds[64][512];  // 64 lines x 1 KB = 64 KB

    const int bx = blockIdx.x;        // 0..255
    const int s  = bx >> 1;           // K-split 0..127 (batches 4s..4s+3)
    const int pt = bx & 1;
    const int tid = threadIdx.x;
    const int lane = tid & 63, wave = tid >> 6;
    const int wp = wave & 3, wq = wave >> 2;
    const int l15 = lane & 15, l4 = lane >> 4;

    const int q = tid & 255, hh = tid >> 8;   // staging role (wave-uniform hh)
    const int qg = q >> 4, q15 = q & 15;

    floatx4 acc[2][8] = {};

    for (int lb = 0; lb < 4; ++lb) {
        const int b = s * 4 + lb;

        // ---- A prefetch (global fragment lines; vmcnt-ordered before ds use)
        bf16x8 a_pf[4][2];
#pragma unroll
        for (int kc = 0; kc < 4; ++kc)
#pragma unroll
            for (int f = 0; f < 2; ++f) {
                int pg = pt * 8 + wp * 2 + f;
                a_pf[kc][f] = *(const bf16x8*)(
                    trace_t + (((size_t)(b * 4 + kc) * 16 + pg) << 9) + lane * 8);
            }

        // ---- B staging: flat batched loads, no conditionals
        const float* pb = post + (size_t)b * (T_SZ * NPOST) + q;
        if (hh == 0) {
            // octs 0..7 (t 0..63)
#pragma unroll
            for (int half = 0; half < 2; ++half) {
                float x[32];
#pragma unroll
                for (int j = 0; j < 32; ++j)
                    x[j] = pb[(size_t)(half * 32 + j) * NPOST];
#pragma unroll
                for (int o = 0; o < 4; ++o) {
                    int oct = half * 4 + o;
                    uint4 v = make_uint4(pack_trunc2(x[o * 8 + 0], x[o * 8 + 1]),
                                         pack_trunc2(x[o * 8 + 2], x[o * 8 + 3]),
                                         pack_trunc2(x[o * 8 + 4], x[o * 8 + 5]),
                                         pack_trunc2(x[o * 8 + 6], x[o * 8 + 7]));
                    *(uint4*)&B_lds[(oct >> 2) * 16 + qg][(((oct & 3) * 16 + q15)) * 8] = v;
                }
            }
        } else {
            // octs 8..11 (t 64..95)
            float x[32];
#pragma unroll
            for (int j = 0; j < 32; ++j)
                x[j] = pb[(size_t)(64 + j) * NPOST];
            float y[4];
#pragma unroll
            for (int j = 0; j < 4; ++j)
                y[j] = pb[(size_t)(96 + j) * NPOST];
#pragma unroll
            for (int o = 0; o < 4; ++o) {
                int oct = 8 + o;
                uint4 v = make_uint4(pack_trunc2(x[o * 8 + 0], x[o * 8 + 1]),
                                     pack_trunc2(x[o * 8 + 2], x[o * 8 + 3]),
                                     pack_trunc2(x[o * 8 + 4], x[o * 8 + 5]),
                                     pack_trunc2(x[o * 8 + 6], x[o * 8 + 7]));
                *(uint4*)&B_lds[(oct >> 2) * 16 + qg][(((oct & 3) * 16 + q15)) * 8] = v;
            }
            // oct 12: t 96..99 real, 100..103 zero
            {
                uint4 v = make_uint4(pack_trunc2(y[0], y[1]),
                                     pack_trunc2(y[2], y[3]), 0u, 0u);
                *(uint4*)&B_lds[3 * 16 + qg][((0 * 16 + q15)) * 8] = v;
            }
            // octs 13..15: zero
#pragma unroll
            for (int o = 13; o < 16; ++o)
                *(uint4*)&B_lds[3 * 16 + qg][(((o & 3) * 16 + q15)) * 8] =
                    make_uint4(0u, 0u, 0u, 0u);
        }
        __syncthreads();

        // ---- MFMA: 4 chunks of K=32
#pragma unroll
        for (int kc = 0; kc < 4; ++kc) {
            bf16x8 bb[8];
#pragma unroll
            for (int g = 0; g < 8; ++g)
                bb[g] = *(const bf16x8*)&B_lds[kc * 16 + wq * 8 + g][lane * 8];
#pragma unroll
            for (int f = 0; f < 2; ++f)
#pragma unroll
                for (int g = 0; g < 8; ++g)
                    acc[f][g] = __builtin_amdgcn_mfma_f32_16x16x32_bf16(
                        a_pf[kc][f], bb[g], acc[f][g], 0, 0, 0);
        }
        __syncthreads();
    }

    // ---- writeout: partial[bx][p_loc 128][q 256]; 64 B-aligned full lines
    // C/D layout (m89/m91): col = lane&15, row = (lane>>4)*4 + reg
    float* pout = partial + (size_t)bx * (128 * 256);
#pragma unroll
    for (int f = 0; f < 2; ++f) {
        int r0 = wp * 32 + f * 16 + l4 * 4;
#pragma unroll
        for (int g = 0; g < 8; ++g) {
            int c = wq * 128 + g * 16 + l15;
#pragma unroll
            for (int v = 0; v < 4; ++v)
                pout[(size_t)(r0 + v) * 256 + c] = acc[f][g][v];
        }
    }
}

// ---------------------------------------------------------------------------
// Kernel 3: reduce 128 K-splits, 8 independent chains/thread, coalesced.
// out[P][Q] = scale * sum_s partial[(s*2 + (P>>7))*32768 + (P&127)*256 + Q]
// ---------------------------------------------------------------------------
__global__ __launch_bounds__(256) void stdp_reduce(
    const float* __restrict__ partial, float* __restrict__ out)
{
    const int idx = blockIdx.x * 256 + threadIdx.x;  // 0..65535
    const int P = idx >> 8, Q = idx & 255;
    const float* src = partial + (size_t)(P >> 7) * 32768 +
                       (size_t)(P & 127) * 256 + Q;
    float a8[8] = {};
#pragma unroll
    for (int i = 0; i < 16; ++i)
#pragma unroll
        for (int u = 0; u < 8; ++u)
            a8[u] += src[(size_t)((u * 16 + i) * 2) * 32768];
    float sum = ((a8[0] + a8[1]) + (a8[2] + a8[3])) +
                ((a8[4] + a8[5]) + (a8[6] + a8[7]));
    const float scale = (0.005f - 0.00525f) * (1.0f / (float)KTOT);
    out[idx] = sum * scale;
}

// ---------------------------------------------------------------------------
extern "C" void kernel_launch(void* const* d_in, const int* in_sizes, int n_in,
                              void* d_out, int out_size, void* d_ws, size_t ws_size,
                              hipStream_t stream)
{
    const float* pre  = (const float*)d_in[0];   // [512,100,256]
    const float* post = (const float*)d_in[1];   // [512,100,256]
    float* out = (float*)d_out;                  // [256,256]

    // ws: trace_t (33,554,432 B) | partial (33,554,432 B) = 67.1 MB
    unsigned short* trace_t = (unsigned short*)d_ws;
    float* partial = (float*)((char*)d_ws + (size_t)33554432);

    stdp_trace_prep<<<512, 256, 0, stream>>>(pre, trace_t);
    stdp_gemm<<<256, 512, 0, stream>>>(trace_t, post, partial);
    stdp_reduce<<<256, 256, 0, stream>>>(partial, out);
}